// Round 7
// baseline (327.219 us; speedup 1.0000x reference)
//
#include <hip/hip_runtime.h>
#include <math.h>

#define NP 20000
#define NG 5000
#define NTOT 25000
#define DF 512
#define NCLS 1000
#define DH 128
#define EPP 240000
#define EPG 100000
#define EGP 100000
#define ETOT 440000
#define FS 8    // fill stride (one counter per 32B)
#define HB 16   // partial-histogram blocks per job

typedef __attribute__((ext_vector_type(8))) __bf16 bf16x8;
typedef __attribute__((ext_vector_type(4))) float f32x4;

__device__ __forceinline__ void gl2lds16(const void* g, void* l) {
    __builtin_amdgcn_global_load_lds(
        (const __attribute__((address_space(1))) unsigned int*)g,
        (__attribute__((address_space(3))) unsigned int*)l, 16, 0, 0);
}

__device__ __forceinline__ float b2f(unsigned short u) {
    union { unsigned int i; float f; } c; c.i = ((unsigned int)u) << 16; return c.f;
}

// ---------------- partial histograms: HB blocks/job, LDS-private, plain stores ----------------
__global__ __launch_bounds__(1024) void hist_part_kernel(
    const int* __restrict__ src_pp, const int* __restrict__ dst_pp,
    const int* __restrict__ src_pg, const int* __restrict__ dst_pg,
    const int* __restrict__ src_gp, const int* __restrict__ dst_gp,
    int* __restrict__ partial)
{
    __shared__ int bins[20000];
    const int job = blockIdx.y, b = blockIdx.x;
    const int* idx; int nbins, nedge; size_t pbase;
    switch (job) {
    case 0: idx = src_pp; nbins = 20000; nedge = EPP; pbase = 0;       break;
    case 1: idx = dst_pp; nbins = 20000; nedge = EPP; pbase = 320000;  break;
    case 2: idx = src_pg; nbins = 20000; nedge = EPG; pbase = 640000;  break;
    case 3: idx = dst_pg; nbins = 5000;  nedge = EPG; pbase = 960000;  break;
    case 4: idx = src_gp; nbins = 5000;  nedge = EGP; pbase = 1040000; break;
    default: idx = dst_gp; nbins = 20000; nedge = EGP; pbase = 1120000; break;
    }
    for (int i = threadIdx.x; i < nbins; i += 1024) bins[i] = 0;
    __syncthreads();
    const int chunk = (nedge + HB - 1) / HB;
    const int e0 = b * chunk, e1 = min(e0 + chunk, nedge);
    for (int e = e0 + threadIdx.x; e < e1; e += 1024) atomicAdd(&bins[idx[e]], 1);
    __syncthreads();
    int* dst = partial + pbase + (size_t)b * nbins;
    for (int i = threadIdx.x; i < nbins; i += 1024) dst[i] = bins[i];
}

// ---------------- merge partials -> degree arrays ----------------
__global__ __launch_bounds__(256) void hist_merge_kernel(const int* __restrict__ partial,
    int* __restrict__ outdeg_pp, int* __restrict__ indeg_pp,
    int* __restrict__ outdeg_pg, int* __restrict__ indeg_pg,
    int* __restrict__ outdeg_gp, int* __restrict__ indeg_gp)
{
    const int job = blockIdx.y;
    const int nbins = (job == 3 || job == 4) ? 5000 : 20000;
    const int bin = blockIdx.x * 256 + threadIdx.x;
    if (bin >= nbins) return;
    size_t pbase; int* outp;
    switch (job) {
    case 0: pbase = 0;       outp = outdeg_pp; break;
    case 1: pbase = 320000;  outp = indeg_pp;  break;
    case 2: pbase = 640000;  outp = outdeg_pg; break;
    case 3: pbase = 960000;  outp = indeg_pg;  break;
    case 4: pbase = 1040000; outp = outdeg_gp; break;
    default: pbase = 1120000; outp = indeg_gp; break;
    }
    const int* p = partial + pbase + bin;
    int s = 0;
#pragma unroll
    for (int b = 0; b < HB; b++) s += p[(size_t)b * nbins];
    outp[bin] = s;
}

// ---------------- exclusive scan -> row_ptr[NTOT+1] ----------------
__global__ __launch_bounds__(1024) void scan_kernel(const int* __restrict__ indeg_pp,
                                                    const int* __restrict__ indeg_gp,
                                                    const int* __restrict__ indeg_pg,
                                                    int* __restrict__ row_ptr)
{
    __shared__ int part[1024];
    int t = threadIdx.x;
    const int CH = (NTOT + 1023) / 1024;
    int base = t * CH;
    auto cntf = [&](int idx) -> int {
        return (idx < NP) ? (indeg_pp[idx] + indeg_gp[idx]) : indeg_pg[idx - NP];
    };
    int s = 0;
    for (int i = 0; i < CH; i++) { int idx = base + i; if (idx < NTOT) s += cntf(idx); }
    part[t] = s;
    __syncthreads();
    for (int off = 1; off < 1024; off <<= 1) {
        int v = (t >= off) ? part[t - off] : 0;
        __syncthreads();
        part[t] += v;
        __syncthreads();
    }
    int run = (t == 0) ? 0 : part[t - 1];
    for (int i = 0; i < CH; i++) {
        int idx = base + i;
        if (idx < NTOT) { row_ptr[idx] = run; run += cntf(idx); }
    }
    if (t == 1023) row_ptr[NTOT] = part[1023];
}

// ---------------- scatter edges into CSR ----------------
__global__ void scatter_kernel(const int* __restrict__ src_pp, const int* __restrict__ dst_pp,
                               const int* __restrict__ src_pg, const int* __restrict__ dst_pg,
                               const int* __restrict__ src_gp, const int* __restrict__ dst_gp,
                               const int* __restrict__ outdeg_pp, const int* __restrict__ outdeg_pg,
                               const int* __restrict__ outdeg_gp,
                               const int* __restrict__ row_ptr, int* fill,
                               int2* __restrict__ edata)
{
    int e = blockIdx.x * blockDim.x + threadIdx.x;
    int s, d, t; float sc;
    if (e < EPP) {
        s = src_pp[e]; d = dst_pp[e]; t = 0;
        sc = rsqrtf((float)max(outdeg_pp[s], 1));
    } else if (e < EPP + EPG) {
        int i = e - EPP; s = src_pg[i]; d = NP + dst_pg[i]; t = 1;
        sc = rsqrtf((float)max(outdeg_pg[s], 1));
    } else if (e < ETOT) {
        int i = e - EPP - EPG; int sl = src_gp[i]; s = NP + sl; d = dst_gp[i]; t = 2;
        sc = rsqrtf((float)max(outdeg_gp[sl], 1));
    } else return;
    int pos = row_ptr[d] + atomicAdd(&fill[d * FS], 1);
    edata[pos] = make_int2(s | (t << 16), __float_as_int(sc));
}

// ---------------- pack go features to padded bf16 [5056][1024] ----------------
__global__ __launch_bounds__(256) void conv_xg_kernel(const float* __restrict__ xg, __bf16* __restrict__ xgb)
{
    long long e = ((long long)blockIdx.x * 256 + threadIdx.x) * 8;
    if (e >= (long long)5056 * 1024) return;
    int row = (int)(e >> 10), k = (int)(e & 1023);
    __bf16 pk[8];
    if (row < NG && k + 7 < 1000) {
        f32x4 v0 = *(const f32x4*)(xg + (size_t)row * 1000 + k);
        f32x4 v1 = *(const f32x4*)(xg + (size_t)row * 1000 + k + 4);
#pragma unroll
        for (int i = 0; i < 4; i++) { pk[i] = (__bf16)v0[i]; pk[4 + i] = (__bf16)v1[i]; }
    } else {
#pragma unroll
        for (int i = 0; i < 8; i++) {
            int kk = k + i;
            pk[i] = (__bf16)((row < NG && kk < 1000) ? xg[(size_t)row * 1000 + kk] : 0.f);
        }
    }
    *(bf16x8*)(xgb + e) = *(bf16x8*)pk;
}

// ---------------- transpose weights to k-major bf16 [N][K] ----------------
__global__ __launch_bounds__(256) void conv_w_kernel(
    const float* W1p, const float* W1g, const float* Wlp, const float* Wrp, const float* Wrg,
    const float* Wnl, const float* Wnr, const float* Wfc,
    __bf16* w1pt, __bf16* w1gt, __bf16* wlpt, __bf16* wrpt, __bf16* wrgt,
    __bf16* wnlt, __bf16* wnrt, __bf16* wfct)
{
    int e = blockIdx.x * 256 + threadIdx.x;
    switch (blockIdx.y) {
    case 0: if (e < 128 * 512)  { int n = e >> 9, k = e & 511;  w1pt[e] = (__bf16)W1p[(size_t)k * 128 + n]; } break;
    case 1: if (e < 128 * 1024) { int n = e >> 10, k = e & 1023; w1gt[e] = (__bf16)(k < 1000 ? W1g[(size_t)k * 128 + n] : 0.f); } break;
    case 2: if (e < 16384) { int n = e >> 7, k = e & 127; wlpt[e] = (__bf16)Wlp[(size_t)k * 128 + n]; } break;
    case 3: if (e < 16384) { int n = e >> 7, k = e & 127; wrpt[e] = (__bf16)Wrp[(size_t)k * 128 + n]; } break;
    case 4: if (e < 16384) { int n = e >> 7, k = e & 127; wrgt[e] = (__bf16)Wrg[(size_t)k * 128 + n]; } break;
    case 5: if (e < 16384) { int n = e >> 7, k = e & 127; wnlt[e] = (__bf16)Wnl[(size_t)k * 128 + n]; } break;
    case 6: if (e < 16384) { int n = e >> 7, k = e & 127; wnrt[e] = (__bf16)Wnr[(size_t)k * 128 + n]; } break;
    case 7: if (e < 1024 * 128) { int n = e >> 7, k = e & 127; wfct[e] = (__bf16)(n < 1000 ? Wfc[(size_t)k * 1000 + n] : 0.f); } break;
    }
}

// =====================================================================
// MFMA bf16 GEMM, global_load_lds staging. Tile 64x128, BK=32.
//   ACT: 0 none, 2 row-l2norm (N==128, gridDim.y==1)
//   DUALW: O2(bf16 under EMIT==4) = A@B2 + b2
//   EMIT: 0 -> O1 fp32; 2 -> Ob bf16 dense; 3 -> Ob dense + Oi[row*256+2c] (x slot)
//         4 -> Oi[row*256+2c+1] (hl slot)
//   AF32: A1 is fp32 (staged 2x16B/lane, cvt in-register); rows clamped to M-1
// =====================================================================
struct GJob {
    const void* A1; const __bf16* B1; const __bf16* B2;
    const float* b1; const float* b2;
    float* O1; void* O2; __bf16* Ob; __bf16* Oi;
    int M, N, Kp, ksteps;
};

template<int ACT, int DUALW, int EMIT, int AF32>
__global__ __launch_bounds__(256) void gemm_bt(GJob j)
{
    __shared__ __align__(16) __bf16 As[AF32 ? 8 : 64 * 32];
    __shared__ __align__(16) float Asf[AF32 ? 64 * 32 : 4];
    __shared__ __align__(16) __bf16 Bs[128 * 32];
    __shared__ __align__(16) __bf16 B2s[DUALW ? 128 * 32 : 8];
    __shared__ float part[2][64];

    const int tid = threadIdx.x;
    const int wave = tid >> 6, lane = tid & 63;
    const int wr = wave >> 1, wc = wave & 1;
    const int l15 = lane & 15, lh = lane >> 4;
    const int row0 = blockIdx.x * 64;
    const int col0 = blockIdx.y * 128;

    const __bf16* A1b = (const __bf16*)j.A1;
    const float*  A1f = (const float*)j.A1;

    // bf16-A staging
    const size_t aoff = (size_t)(row0 + (tid >> 2)) * j.Kp + (tid & 3) * 8;
    // fp32-A staging (two 4KB halves, rows clamped)
    const size_t a0off = (size_t)min(row0 + (tid >> 3), j.M - 1) * j.Kp + (tid & 7) * 4;
    const size_t a1off = (size_t)min(row0 + 32 + (tid >> 3), j.M - 1) * j.Kp + (tid & 7) * 4;
    const size_t boff0 = (size_t)(col0 + (tid >> 2)) * j.Kp + (tid & 3) * 8;
    const size_t boff1 = boff0 + (size_t)64 * j.Kp;
    char* alds   = (char*)As + wave * 1024;
    char* aldsf0 = (char*)Asf + wave * 1024;
    char* aldsf1 = (char*)Asf + 4096 + wave * 1024;
    char* blds0  = (char*)Bs + wave * 1024;
    char* blds1  = (char*)Bs + 4096 + wave * 1024;
    char* b2lds0 = (char*)B2s + wave * 1024;
    char* b2lds1 = (char*)B2s + 4096 + wave * 1024;

    f32x4 acc[2][4], acc2[2][4];
#pragma unroll
    for (int fm = 0; fm < 2; fm++)
#pragma unroll
        for (int fn = 0; fn < 4; fn++) {
            acc[fm][fn] = (f32x4)0.f;
            if (DUALW) acc2[fm][fn] = (f32x4)0.f;
        }

    for (int ks = 0; ks < j.ksteps; ks++) {
        const int k0 = ks * 32;
        __syncthreads();
        if constexpr (AF32) {
            gl2lds16(A1f + a0off + k0, aldsf0);
            gl2lds16(A1f + a1off + k0, aldsf1);
        } else {
            gl2lds16(A1b + aoff + k0, alds);
        }
        gl2lds16(j.B1 + boff0 + k0, blds0);
        gl2lds16(j.B1 + boff1 + k0, blds1);
        if constexpr (DUALW) {
            gl2lds16(j.B2 + boff0 + k0, b2lds0);
            gl2lds16(j.B2 + boff1 + k0, b2lds1);
        }
        __syncthreads();

#pragma unroll
        for (int fm = 0; fm < 2; fm++) {
            bf16x8 a;
            if constexpr (AF32) {
                const float* ap = &Asf[(wr * 32 + fm * 16 + l15) * 32 + lh * 8];
                f32x4 a0 = *(const f32x4*)ap;
                f32x4 a1 = *(const f32x4*)(ap + 4);
                __bf16 pk[8];
#pragma unroll
                for (int i = 0; i < 4; i++) { pk[i] = (__bf16)a0[i]; pk[4 + i] = (__bf16)a1[i]; }
                a = *(bf16x8*)pk;
            } else {
                a = *(const bf16x8*)&As[(wr * 32 + fm * 16 + l15) * 32 + lh * 8];
            }
#pragma unroll
            for (int fn = 0; fn < 4; fn++) {
                bf16x8 b = *(const bf16x8*)&Bs[(wc * 64 + fn * 16 + l15) * 32 + lh * 8];
                acc[fm][fn] = __builtin_amdgcn_mfma_f32_16x16x32_bf16(a, b, acc[fm][fn], 0, 0, 0);
                if constexpr (DUALW) {
                    bf16x8 b2 = *(const bf16x8*)&B2s[(wc * 64 + fn * 16 + l15) * 32 + lh * 8];
                    acc2[fm][fn] = __builtin_amdgcn_mfma_f32_16x16x32_bf16(a, b2, acc2[fm][fn], 0, 0, 0);
                }
            }
        }
    }

    // ---- epilogue ----
    float bias[4], bias2[4];
#pragma unroll
    for (int fn = 0; fn < 4; fn++) {
        int col = col0 + wc * 64 + fn * 16 + l15;
        bias[fn] = 0.f; bias2[fn] = 0.f;
        if (col < j.N) {
            bias[fn] = j.b1[col];
            if (DUALW) bias2[fn] = j.b2[col];
        }
    }

    float vv[2][4][4];
#pragma unroll
    for (int fm = 0; fm < 2; fm++)
#pragma unroll
        for (int fn = 0; fn < 4; fn++)
#pragma unroll
            for (int r = 0; r < 4; r++) vv[fm][fn][r] = acc[fm][fn][r] + bias[fn];

    float scale[2][4];
#pragma unroll
    for (int fm = 0; fm < 2; fm++)
#pragma unroll
        for (int r = 0; r < 4; r++) scale[fm][r] = 1.f;

    if constexpr (ACT == 2) {
        float s[2][4];
#pragma unroll
        for (int fm = 0; fm < 2; fm++)
#pragma unroll
            for (int r = 0; r < 4; r++) {
                float v = 0.f;
#pragma unroll
                for (int fn = 0; fn < 4; fn++) v += vv[fm][fn][r] * vv[fm][fn][r];
                v += __shfl_xor(v, 1);
                v += __shfl_xor(v, 2);
                v += __shfl_xor(v, 4);
                v += __shfl_xor(v, 8);
                s[fm][r] = v;
            }
        __syncthreads();
        if (l15 == 0) {
#pragma unroll
            for (int fm = 0; fm < 2; fm++)
#pragma unroll
                for (int r = 0; r < 4; r++)
                    part[wc][wr * 32 + fm * 16 + lh * 4 + r] = s[fm][r];
        }
        __syncthreads();
#pragma unroll
        for (int fm = 0; fm < 2; fm++)
#pragma unroll
            for (int r = 0; r < 4; r++) {
                int rl = wr * 32 + fm * 16 + lh * 4 + r;
                float ss = part[0][rl] + part[1][rl];
                scale[fm][r] = 1.f / fmaxf(sqrtf(ss), 1e-12f);
            }
    }

#pragma unroll
    for (int fm = 0; fm < 2; fm++)
#pragma unroll
        for (int fn = 0; fn < 4; fn++)
#pragma unroll
            for (int r = 0; r < 4; r++) {
                int row = row0 + wr * 32 + fm * 16 + lh * 4 + r;
                int col = col0 + wc * 64 + fn * 16 + l15;
                if (row < j.M && col < j.N) {
                    float v = vv[fm][fn][r] * scale[fm][r];
                    if constexpr (EMIT == 0) j.O1[(size_t)row * j.N + col] = v;
                    if constexpr (EMIT == 2) j.Ob[(size_t)row * j.N + col] = (__bf16)v;
                    if constexpr (EMIT == 3) {
                        j.Ob[(size_t)row * j.N + col] = (__bf16)v;
                        j.Oi[(size_t)row * 256 + col * 2] = (__bf16)v;
                    }
                    if constexpr (EMIT == 4) j.Oi[(size_t)row * 256 + col * 2 + 1] = (__bf16)v;
                    if constexpr (DUALW)
                        ((__bf16*)j.O2)[(size_t)row * j.N + col] = (__bf16)(acc2[fm][fn][r] + bias2[fn]);
                }
            }
}

// =====================================================================
// Fused ea+wa: accL=x@Wl (shared), accP=rpp@Wrp, accG=rgp@Wrg;
// epilogue: app=elu(accL+accP+blp+brp), agp=elu(accL+accG+blp+brg),
// then per-(node,ch) type-softmax weights -> wpp/wgp fp32.
// =====================================================================
__global__ __launch_bounds__(256) void ea_wa_kernel(
    const __bf16* __restrict__ xb, const __bf16* __restrict__ rppb, const __bf16* __restrict__ rgpb,
    const __bf16* __restrict__ wl, const __bf16* __restrict__ wrp, const __bf16* __restrict__ wrg,
    const float* __restrict__ blp, const float* __restrict__ brp, const float* __restrict__ brg,
    const int* __restrict__ indeg_pp, const int* __restrict__ indeg_gp,
    float* __restrict__ wpp, float* __restrict__ wgp)
{
    __shared__ __align__(16) __bf16 A1s[64 * 32], A2s[64 * 32], A3s[64 * 32];
    __shared__ __align__(16) __bf16 B1s[128 * 32], B2s[128 * 32], B3s[128 * 32];

    const int tid = threadIdx.x;
    const int wave = tid >> 6, lane = tid & 63;
    const int wr = wave >> 1, wc = wave & 1;
    const int l15 = lane & 15, lh = lane >> 4;
    const int row0 = blockIdx.x * 64;

    const size_t aoff = (size_t)(row0 + (tid >> 2)) * 128 + (tid & 3) * 8;
    const size_t boff0 = (size_t)(tid >> 2) * 128 + (tid & 3) * 8;
    const size_t boff1 = boff0 + (size_t)64 * 128;
    char* a1 = (char*)A1s + wave * 1024;
    char* a2 = (char*)A2s + wave * 1024;
    char* a3 = (char*)A3s + wave * 1024;
    char* b1l0 = (char*)B1s + wave * 1024, *b1l1 = (char*)B1s + 4096 + wave * 1024;
    char* b2l0 = (char*)B2s + wave * 1024, *b2l1 = (char*)B2s + 4096 + wave * 1024;
    char* b3l0 = (char*)B3s + wave * 1024, *b3l1 = (char*)B3s + 4096 + wave * 1024;

    f32x4 accL[2][4], accP[2][4], accG[2][4];
#pragma unroll
    for (int fm = 0; fm < 2; fm++)
#pragma unroll
        for (int fn = 0; fn < 4; fn++) {
            accL[fm][fn] = (f32x4)0.f; accP[fm][fn] = (f32x4)0.f; accG[fm][fn] = (f32x4)0.f;
        }

    for (int ks = 0; ks < 4; ks++) {
        const int k0 = ks * 32;
        __syncthreads();
        gl2lds16(xb + aoff + k0, a1);
        gl2lds16(rppb + aoff + k0, a2);
        gl2lds16(rgpb + aoff + k0, a3);
        gl2lds16(wl + boff0 + k0, b1l0);  gl2lds16(wl + boff1 + k0, b1l1);
        gl2lds16(wrp + boff0 + k0, b2l0); gl2lds16(wrp + boff1 + k0, b2l1);
        gl2lds16(wrg + boff0 + k0, b3l0); gl2lds16(wrg + boff1 + k0, b3l1);
        __syncthreads();

#pragma unroll
        for (int fm = 0; fm < 2; fm++) {
            const int arow = (wr * 32 + fm * 16 + l15) * 32 + lh * 8;
            bf16x8 aL = *(const bf16x8*)&A1s[arow];
            bf16x8 aP = *(const bf16x8*)&A2s[arow];
            bf16x8 aG = *(const bf16x8*)&A3s[arow];
#pragma unroll
            for (int fn = 0; fn < 4; fn++) {
                const int brow = (wc * 64 + fn * 16 + l15) * 32 + lh * 8;
                bf16x8 bL = *(const bf16x8*)&B1s[brow];
                bf16x8 bP = *(const bf16x8*)&B2s[brow];
                bf16x8 bG = *(const bf16x8*)&B3s[brow];
                accL[fm][fn] = __builtin_amdgcn_mfma_f32_16x16x32_bf16(aL, bL, accL[fm][fn], 0, 0, 0);
                accP[fm][fn] = __builtin_amdgcn_mfma_f32_16x16x32_bf16(aP, bP, accP[fm][fn], 0, 0, 0);
                accG[fm][fn] = __builtin_amdgcn_mfma_f32_16x16x32_bf16(aG, bG, accG[fm][fn], 0, 0, 0);
            }
        }
    }

    float bp[4], bg[4];
#pragma unroll
    for (int fn = 0; fn < 4; fn++) {
        int col = wc * 64 + fn * 16 + l15;
        bp[fn] = blp[col] + brp[col];
        bg[fn] = blp[col] + brg[col];
    }

#pragma unroll
    for (int fm = 0; fm < 2; fm++)
#pragma unroll
        for (int r = 0; r < 4; r++) {
            int row = row0 + wr * 32 + fm * 16 + lh * 4 + r;
            int rr = min(row, NP - 1);
            int npp = indeg_pp[rr], ngp = indeg_gp[rr];
#pragma unroll
            for (int fn = 0; fn < 4; fn++) {
                int col = wc * 64 + fn * 16 + l15;
                float app = accL[fm][fn][r] + accP[fm][fn][r] + bp[fn];
                app = app > 0.f ? app : (__expf(app) - 1.f);
                float agp = accL[fm][fn][r] + accG[fm][fn][r] + bg[fn];
                agp = agp > 0.f ? agp : (__expf(agp) - 1.f);
                float wppv = 0.f, wgpv = 0.f;
                if (npp > 0 && ngp > 0) {
                    float mx = fmaxf(app, agp);
                    float ep = __expf(app - mx), eg = __expf(agp - mx);
                    float den = (float)npp * ep + (float)ngp * eg;
                    wppv = ep / den; wgpv = eg / den;
                } else if (npp > 0) wppv = 1.f / (float)npp;
                else if (ngp > 0) wgpv = 1.f / (float)ngp;
                if (row < NP) {
                    wpp[(size_t)row * DH + col] = wppv;
                    wgp[(size_t)row * DH + col] = wgpv;
                }
            }
        }
}

// ---------------- GCN aggregation (2-edge ILP, bf16 gather) ----------------
__global__ __launch_bounds__(256) void rst_agg_kernel(const __bf16* __restrict__ x,
                                                      const int* __restrict__ row_ptr,
                                                      const int2* __restrict__ edata,
                                                      const int* __restrict__ indeg_pp,
                                                      const int* __restrict__ indeg_gp,
                                                      __bf16* __restrict__ rppb, __bf16* __restrict__ rgpb)
{
    int d = blockIdx.x;  // < NP
    int tid = threadIdx.x;
    int c = tid & 127, h = tid >> 7;
    int beg = row_ptr[d], end = row_ptr[d + 1];
    float spp = 0.f, sgp = 0.f;
    __shared__ int pl[128];
    __shared__ float sc[128];
    __shared__ float red[2][2][128];
    const unsigned short* xu = (const unsigned short*)x;
    for (int base = beg; base < end; base += 128) {
        int n = min(128, end - base);
        __syncthreads();
        if (tid < n) { int2 e2 = edata[base + tid]; pl[tid] = e2.x; sc[tid] = __int_as_float(e2.y); }
        __syncthreads();
        for (int i = h; i < n; i += 2) {
            int p = pl[i]; int s = p & 0xFFFF; int t = p >> 16;
            float v = b2f(xu[(size_t)s * DH + c]) * sc[i];
            if (t == 0) spp += v; else sgp += v;
        }
    }
    red[h][0][c] = spp; red[h][1][c] = sgp;
    __syncthreads();
    if (h == 0) {
        float tp = spp + red[1][0][c];
        float tg = sgp + red[1][1][c];
        float ipp = rsqrtf((float)max(indeg_pp[d], 1));
        float igp = rsqrtf((float)max(indeg_gp[d], 1));
        rppb[(size_t)d * DH + c] = (__bf16)(tp * ipp);
        rgpb[(size_t)d * DH + c] = (__bf16)(tg * igp);
    }
}

// ---------------- node attention: packed x+hl gather, 2-edge ILP, branchless ----------------
__global__ __launch_bounds__(256) void node_attn_kernel(const __bf16* __restrict__ xhl,
                                                        const __bf16* __restrict__ hrb,
                                                        const float* __restrict__ wpp_arr, const float* __restrict__ wgp_arr,
                                                        const int* __restrict__ indeg_pg,
                                                        const int* __restrict__ row_ptr, const int2* __restrict__ edata,
                                                        __bf16* __restrict__ hb)
{
    int d = blockIdx.x;
    int tid = threadIdx.x;
    int c = tid & 127, h = tid >> 7;
    int beg = row_ptr[d], end = row_ptr[d + 1];
    float hrd = b2f(((const unsigned short*)hrb)[(size_t)d * DH + c]);
    float wppv, wgpv;
    if (d < NP) {
        wppv = wpp_arr[(size_t)d * DH + c];
        wgpv = wgp_arr[(size_t)d * DH + c];
    } else {
        float w = 1.f / (float)max(indeg_pg[d - NP], 1);
        wppv = w; wgpv = w;
    }
    float ssum = 0.f, acc = 0.f;
    __shared__ int pl[128];
    __shared__ float red[2][2][128];
    const unsigned int* xu = (const unsigned int*)xhl;  // dword = {x(lo), hl(hi)} per channel
    for (int base = beg; base < end; base += 128) {
        int n = min(128, end - base);
        __syncthreads();
        if (tid < n) pl[tid] = edata[base + tid].x;
        __syncthreads();
        for (int i = h; i < n; i += 2) {
            int p = pl[i]; int s = p & 0xFFFF; int t = p >> 16;
            unsigned int u = xu[(size_t)s * 128 + c];
            float xv  = b2f((unsigned short)(u & 0xFFFFu));
            float hlv = b2f((unsigned short)(u >> 16));
            float al = (t == 0) ? wppv : wgpv;
            float e = (hlv + hrd) * al;
            e = fmaxf(e, -0.2f * e);          // LeakyReLU slope -0.2
            float pw = __expf(e);
            ssum += pw;
            acc += pw * xv;
        }
    }
    red[h][0][c] = ssum; red[h][1][c] = acc;
    __syncthreads();
    if (h == 0) {
        float ts = ssum + red[1][0][c];
        float ta = acc + red[1][1][c];
        hb[(size_t)d * DH + c] = (__bf16)((end > beg) ? ta / ts : 0.f);
    }
}

extern "C" void kernel_launch(void* const* d_in, const int* in_sizes, int n_in,
                              void* d_out, int out_size, void* d_ws, size_t ws_size,
                              hipStream_t stream)
{
    const float* x_protein = (const float*)d_in[0];
    const float* x_go      = (const float*)d_in[1];
    const int* src_pp = (const int*)d_in[2];
    const int* dst_pp = (const int*)d_in[3];
    const int* src_pg = (const int*)d_in[4];
    const int* dst_pg = (const int*)d_in[5];
    const int* src_gp = (const int*)d_in[6];
    const int* dst_gp = (const int*)d_in[7];
    const float* W1p = (const float*)d_in[8];
    const float* b1p = (const float*)d_in[9];
    const float* W1g = (const float*)d_in[10];
    const float* b1g = (const float*)d_in[11];
    const float* Wl_p = (const float*)d_in[12];
    const float* bl_p = (const float*)d_in[13];
    // Wl_g (14), bl_g (15) dead: go-dst type-alpha is uniform 1/n
    const float* Wr_p = (const float*)d_in[16];
    const float* br_p = (const float*)d_in[17];
    const float* Wr_g = (const float*)d_in[18];
    const float* br_g = (const float*)d_in[19];
    const float* Wnl = (const float*)d_in[20];
    const float* bnl = (const float*)d_in[21];
    const float* Wnr = (const float*)d_in[22];
    const float* bnr = (const float*)d_in[23];
    const float* Wfc = (const float*)d_in[24];
    const float* bfc = (const float*)d_in[25];
    float* out = (float*)d_out;

    // ---- workspace layout (4B words); total ~68 MB ----
    size_t off = 0;
    char* base = (char*)d_ws;
    auto alloc = [&](size_t words) { void* p = base + off * 4; off += (words + 7) & ~(size_t)7; return p; };

    __bf16* xb   = (__bf16*)alloc((size_t)25024 * 128 / 2);  // dense x (rst_agg, ea, hlr A)
    __bf16* xhl  = (__bf16*)alloc((size_t)25024 * 256 / 2);  // interleaved {x, hl} per channel
    __bf16* hrb  = (__bf16*)alloc((size_t)25024 * 128 / 2);  // hr bf16 dense
    __bf16* rppb = (__bf16*)alloc((size_t)20032 * 128 / 2);
    __bf16* rgpb = (__bf16*)alloc((size_t)20032 * 128 / 2);
    // R1: hist partials -> xgb -> {wpp, wgp, haggb}
    char* R1 = (char*)alloc(6722000);
    int*    partial = (int*)R1;                              // 16*90000 ints
    __bf16* xgb = (__bf16*)R1;                               // 5056*1024
    float*  wpp = (float*)R1;                                // 20000*128 f32
    float*  wgp = wpp + (size_t)20000 * 128;
    __bf16* haggb = (__bf16*)(wgp + (size_t)20000 * 128);    // 25024*128
    __bf16* w1pt = (__bf16*)alloc(128 * 512 / 2);
    __bf16* w1gt = (__bf16*)alloc(128 * 1024 / 2);
    __bf16* wlpt = (__bf16*)alloc(128 * 128 / 2);
    __bf16* wrpt = (__bf16*)alloc(128 * 128 / 2);
    __bf16* wrgt = (__bf16*)alloc(128 * 128 / 2);
    __bf16* wnlt = (__bf16*)alloc(128 * 128 / 2);
    __bf16* wnrt = (__bf16*)alloc(128 * 128 / 2);
    __bf16* wfct = (__bf16*)alloc(1024 * 128 / 2);
    int* outdeg_pp = (int*)alloc(NP);
    int* outdeg_pg = (int*)alloc(NP);
    int* outdeg_gp = (int*)alloc(NG);
    int* indeg_pp  = (int*)alloc(NP);
    int* indeg_gp  = (int*)alloc(NP);
    int* indeg_pg  = (int*)alloc(NG);
    int* fill      = (int*)alloc((size_t)NTOT * FS);
    int* row_ptr   = (int*)alloc(NTOT + 1);
    int2* edata    = (int2*)alloc((size_t)ETOT * 2);

    hipMemsetAsync(fill, 0, (size_t)NTOT * FS * sizeof(int), stream);

    hist_part_kernel<<<dim3(HB, 6), 1024, 0, stream>>>(
        src_pp, dst_pp, src_pg, dst_pg, src_gp, dst_gp, partial);
    hist_merge_kernel<<<dim3((20000 + 255) / 256, 6), 256, 0, stream>>>(
        partial, outdeg_pp, indeg_pp, outdeg_pg, indeg_pg, outdeg_gp, indeg_gp);
    scan_kernel<<<1, 1024, 0, stream>>>(indeg_pp, indeg_gp, indeg_pg, row_ptr);
    scatter_kernel<<<(ETOT + 255) / 256, 256, 0, stream>>>(
        src_pp, dst_pp, src_pg, dst_pg, src_gp, dst_gp,
        outdeg_pp, outdeg_pg, outdeg_gp, row_ptr, fill, edata);

    conv_xg_kernel<<<2528, 256, 0, stream>>>(x_go, xgb);
    conv_w_kernel<<<dim3(512, 8), 256, 0, stream>>>(W1p, W1g, Wl_p, Wr_p, Wr_g, Wnl, Wnr, Wfc,
                                                    w1pt, w1gt, wlpt, wrpt, wrgt, wnlt, wnrt, wfct);

    // protein projection + l2norm: fp32 A direct (no conversion pass)
    {
        GJob p = { x_protein, w1pt, nullptr, b1p, nullptr, nullptr, nullptr, xb, xhl, NP, 128, 512, 16 };
        gemm_bt<2, 0, 3, 1><<<313, 256, 0, stream>>>(p);
    }
    // go projection + l2norm (bf16 padded A)
    {
        GJob p = { xgb, w1gt, nullptr, b1g, nullptr, nullptr, nullptr,
                   xb + (size_t)NP * 128, xhl + (size_t)NP * 256, NG, 128, 1024, 32 };
        gemm_bt<2, 0, 3, 0><<<79, 256, 0, stream>>>(p);
    }

    // GCN aggregation for type attention (protein dst only)
    rst_agg_kernel<<<NP, 256, 0, stream>>>(xb, row_ptr, edata, indeg_pp, indeg_gp, rppb, rgpb);

    // fused ea + type-softmax weights
    ea_wa_kernel<<<313, 256, 0, stream>>>(xb, rppb, rgpb, wlpt, wrpt, wrgt,
                                          bl_p, br_p, br_g, indeg_pp, indeg_gp, wpp, wgp);

    // node attention projections: hl -> xhl odd slots, hr -> bf16 dense
    {
        GJob h0 = { xb, wnlt, wnrt, bnl, bnr, nullptr, hrb, nullptr, xhl, NTOT, 128, 128, 4 };
        gemm_bt<0, 1, 4, 0><<<391, 256, 0, stream>>>(h0);
    }

    // node attention + aggregation -> haggb
    node_attn_kernel<<<NTOT, 256, 0, stream>>>(xhl, hrb, wpp, wgp, indeg_pg, row_ptr, edata, haggb);

    // final classifier: out = hagg@Wfc + bfc
    {
        GJob o0 = { haggb, wfct, nullptr, bfc, nullptr, out, nullptr, nullptr, nullptr, NTOT, NCLS, 128, 4 };
        gemm_bt<0, 0, 0, 0><<<dim3(391, 8), 256, 0, stream>>>(o0);
    }

    (void)in_sizes; (void)n_in; (void)out_size; (void)ws_size;
}

// Round 8
// 266.488 us; speedup vs baseline: 1.2279x; 1.2279x over previous
//
#include <hip/hip_runtime.h>
#include <math.h>

#define NP 20000
#define NG 5000
#define NTOT 25000
#define DF 512
#define NCLS 1000
#define DH 128
#define EPP 240000
#define EPG 100000
#define EGP 100000
#define ETOT 440000
#define FS 16   // fill stride (one counter per 64B line)
#define HB 16   // partial-histogram blocks per job

typedef __attribute__((ext_vector_type(8))) __bf16 bf16x8;
typedef __attribute__((ext_vector_type(4))) float f32x4;

__device__ __forceinline__ void gl2lds16(const void* g, void* l) {
    __builtin_amdgcn_global_load_lds(
        (const __attribute__((address_space(1))) unsigned int*)g,
        (__attribute__((address_space(3))) unsigned int*)l, 16, 0, 0);
}

__device__ __forceinline__ float b2f(unsigned short u) {
    union { unsigned int i; float f; } c; c.i = ((unsigned int)u) << 16; return c.f;
}

// ---------------- partial histograms: HB blocks/job, LDS-private, plain stores ----------------
__global__ __launch_bounds__(1024) void hist_part_kernel(
    const int* __restrict__ src_pp, const int* __restrict__ dst_pp,
    const int* __restrict__ src_pg, const int* __restrict__ dst_pg,
    const int* __restrict__ src_gp, const int* __restrict__ dst_gp,
    int* __restrict__ partial)
{
    __shared__ int bins[20000];
    const int job = blockIdx.y, b = blockIdx.x;
    const int* idx; int nbins, nedge; size_t pbase;
    switch (job) {
    case 0: idx = src_pp; nbins = 20000; nedge = EPP; pbase = 0;       break;
    case 1: idx = dst_pp; nbins = 20000; nedge = EPP; pbase = 320000;  break;
    case 2: idx = src_pg; nbins = 20000; nedge = EPG; pbase = 640000;  break;
    case 3: idx = dst_pg; nbins = 5000;  nedge = EPG; pbase = 960000;  break;
    case 4: idx = src_gp; nbins = 5000;  nedge = EGP; pbase = 1040000; break;
    default: idx = dst_gp; nbins = 20000; nedge = EGP; pbase = 1120000; break;
    }
    for (int i = threadIdx.x; i < nbins; i += 1024) bins[i] = 0;
    __syncthreads();
    const int chunk = (nedge + HB - 1) / HB;
    const int e0 = b * chunk, e1 = min(e0 + chunk, nedge);
    for (int e = e0 + threadIdx.x; e < e1; e += 1024) atomicAdd(&bins[idx[e]], 1);
    __syncthreads();
    int* dst = partial + pbase + (size_t)b * nbins;
    for (int i = threadIdx.x; i < nbins; i += 1024) dst[i] = bins[i];
}

// ---------------- merge partials -> degree arrays ----------------
__global__ __launch_bounds__(256) void hist_merge_kernel(const int* __restrict__ partial,
    int* __restrict__ outdeg_pp, int* __restrict__ indeg_pp,
    int* __restrict__ outdeg_pg, int* __restrict__ indeg_pg,
    int* __restrict__ outdeg_gp, int* __restrict__ indeg_gp)
{
    const int job = blockIdx.y;
    const int nbins = (job == 3 || job == 4) ? 5000 : 20000;
    const int bin = blockIdx.x * 256 + threadIdx.x;
    if (bin >= nbins) return;
    size_t pbase; int* outp;
    switch (job) {
    case 0: pbase = 0;       outp = outdeg_pp; break;
    case 1: pbase = 320000;  outp = indeg_pp;  break;
    case 2: pbase = 640000;  outp = outdeg_pg; break;
    case 3: pbase = 960000;  outp = indeg_pg;  break;
    case 4: pbase = 1040000; outp = outdeg_gp; break;
    default: pbase = 1120000; outp = indeg_gp; break;
    }
    const int* p = partial + pbase + bin;
    int s = 0;
#pragma unroll
    for (int b = 0; b < HB; b++) s += p[(size_t)b * nbins];
    outp[bin] = s;
}

// ---------------- exclusive scan -> row_ptr[NTOT+1] ----------------
__global__ __launch_bounds__(1024) void scan_kernel(const int* __restrict__ indeg_pp,
                                                    const int* __restrict__ indeg_gp,
                                                    const int* __restrict__ indeg_pg,
                                                    int* __restrict__ row_ptr)
{
    __shared__ int part[1024];
    int t = threadIdx.x;
    const int CH = (NTOT + 1023) / 1024;
    int base = t * CH;
    auto cntf = [&](int idx) -> int {
        return (idx < NP) ? (indeg_pp[idx] + indeg_gp[idx]) : indeg_pg[idx - NP];
    };
    int s = 0;
    for (int i = 0; i < CH; i++) { int idx = base + i; if (idx < NTOT) s += cntf(idx); }
    part[t] = s;
    __syncthreads();
    for (int off = 1; off < 1024; off <<= 1) {
        int v = (t >= off) ? part[t - off] : 0;
        __syncthreads();
        part[t] += v;
        __syncthreads();
    }
    int run = (t == 0) ? 0 : part[t - 1];
    for (int i = 0; i < CH; i++) {
        int idx = base + i;
        if (idx < NTOT) { row_ptr[idx] = run; run += cntf(idx); }
    }
    if (t == 1023) row_ptr[NTOT] = part[1023];
}

// ---------------- scatter edges into CSR ----------------
__global__ void scatter_kernel(const int* __restrict__ src_pp, const int* __restrict__ dst_pp,
                               const int* __restrict__ src_pg, const int* __restrict__ dst_pg,
                               const int* __restrict__ src_gp, const int* __restrict__ dst_gp,
                               const int* __restrict__ outdeg_pp, const int* __restrict__ outdeg_pg,
                               const int* __restrict__ outdeg_gp,
                               const int* __restrict__ row_ptr, int* fill,
                               int2* __restrict__ edata)
{
    int e = blockIdx.x * blockDim.x + threadIdx.x;
    int s, d, t; float sc;
    if (e < EPP) {
        s = src_pp[e]; d = dst_pp[e]; t = 0;
        sc = rsqrtf((float)max(outdeg_pp[s], 1));
    } else if (e < EPP + EPG) {
        int i = e - EPP; s = src_pg[i]; d = NP + dst_pg[i]; t = 1;
        sc = rsqrtf((float)max(outdeg_pg[s], 1));
    } else if (e < ETOT) {
        int i = e - EPP - EPG; int sl = src_gp[i]; s = NP + sl; d = dst_gp[i]; t = 2;
        sc = rsqrtf((float)max(outdeg_gp[sl], 1));
    } else return;
    int pos = row_ptr[d] + atomicAdd(&fill[d * FS], 1);
    edata[pos] = make_int2(s | (t << 16), __float_as_int(sc));
}

// ---------------- pack inputs to padded bf16 ----------------
__global__ __launch_bounds__(256) void conv_x_kernel(const float* __restrict__ xp, const float* __restrict__ xg,
                                                     __bf16* __restrict__ xpb, __bf16* __restrict__ xgb)
{
    long long e = ((long long)blockIdx.x * 256 + threadIdx.x) * 8;
    __bf16 pk[8];
    if (blockIdx.y == 0) {
        if (e >= (long long)20032 * 512) return;
        int row = (int)(e >> 9), k = (int)(e & 511);
        if (row < NP) {
            f32x4 v0 = *(const f32x4*)(xp + (size_t)row * 512 + k);
            f32x4 v1 = *(const f32x4*)(xp + (size_t)row * 512 + k + 4);
#pragma unroll
            for (int i = 0; i < 4; i++) { pk[i] = (__bf16)v0[i]; pk[4 + i] = (__bf16)v1[i]; }
        } else {
#pragma unroll
            for (int i = 0; i < 8; i++) pk[i] = (__bf16)0.f;
        }
        *(bf16x8*)(xpb + e) = *(bf16x8*)pk;
    } else {
        if (e >= (long long)5056 * 1024) return;
        int row = (int)(e >> 10), k = (int)(e & 1023);
        if (row < NG && k + 7 < 1000) {
            f32x4 v0 = *(const f32x4*)(xg + (size_t)row * 1000 + k);
            f32x4 v1 = *(const f32x4*)(xg + (size_t)row * 1000 + k + 4);
#pragma unroll
            for (int i = 0; i < 4; i++) { pk[i] = (__bf16)v0[i]; pk[4 + i] = (__bf16)v1[i]; }
        } else {
#pragma unroll
            for (int i = 0; i < 8; i++) {
                int kk = k + i;
                pk[i] = (__bf16)((row < NG && kk < 1000) ? xg[(size_t)row * 1000 + kk] : 0.f);
            }
        }
        *(bf16x8*)(xgb + e) = *(bf16x8*)pk;
    }
}

// ---------------- transpose weights to k-major bf16 [N][K] ----------------
__global__ __launch_bounds__(256) void conv_w_kernel(
    const float* W1p, const float* W1g, const float* Wlp, const float* Wrp, const float* Wrg,
    const float* Wnl, const float* Wnr, const float* Wfc,
    __bf16* w1pt, __bf16* w1gt, __bf16* wlpt, __bf16* wrpt, __bf16* wrgt,
    __bf16* wnlt, __bf16* wnrt, __bf16* wfct)
{
    int e = blockIdx.x * 256 + threadIdx.x;
    switch (blockIdx.y) {
    case 0: if (e < 128 * 512)  { int n = e >> 9, k = e & 511;  w1pt[e] = (__bf16)W1p[(size_t)k * 128 + n]; } break;
    case 1: if (e < 128 * 1024) { int n = e >> 10, k = e & 1023; w1gt[e] = (__bf16)(k < 1000 ? W1g[(size_t)k * 128 + n] : 0.f); } break;
    case 2: if (e < 16384) { int n = e >> 7, k = e & 127; wlpt[e] = (__bf16)Wlp[(size_t)k * 128 + n]; } break;
    case 3: if (e < 16384) { int n = e >> 7, k = e & 127; wrpt[e] = (__bf16)Wrp[(size_t)k * 128 + n]; } break;
    case 4: if (e < 16384) { int n = e >> 7, k = e & 127; wrgt[e] = (__bf16)Wrg[(size_t)k * 128 + n]; } break;
    case 5: if (e < 16384) { int n = e >> 7, k = e & 127; wnlt[e] = (__bf16)Wnl[(size_t)k * 128 + n]; } break;
    case 6: if (e < 16384) { int n = e >> 7, k = e & 127; wnrt[e] = (__bf16)Wnr[(size_t)k * 128 + n]; } break;
    case 7: if (e < 1024 * 128) { int n = e >> 7, k = e & 127; wfct[e] = (__bf16)(n < 1000 ? Wfc[(size_t)k * 1000 + n] : 0.f); } break;
    }
}

// =====================================================================
// MFMA bf16 GEMM with global_load_lds staging (round-6 proven structure).
//   ACT: 0 none, 2 row-l2norm (N==128, gridDim.y==1)
//   DUALW: O2 (bf16) = A1@B2 + b2
//   EMIT: 0 -> O1 fp32; 2 -> Ob bf16 only
// =====================================================================
struct GJob {
    const __bf16* A1;
    const __bf16* B1; const __bf16* B2;
    const float* b1; const float* b2;
    float* O1; __bf16* O2; __bf16* Ob;
    int M, N, Kp, ksteps;
};

template<int ACT, int DUALW, int EMIT>
__global__ __launch_bounds__(256) void gemm_bt(GJob j0, GJob j1, int split)
{
    __shared__ __align__(16) __bf16 As[64 * 32];
    __shared__ __align__(16) __bf16 Bs[128 * 32];
    __shared__ __align__(16) __bf16 B2s[DUALW ? 128 * 32 : 8];
    __shared__ float part[2][64];

    GJob j; int bx;
    if ((int)blockIdx.x < split) { j = j0; bx = blockIdx.x; }
    else { j = j1; bx = blockIdx.x - split; }

    const int tid = threadIdx.x;
    const int wave = tid >> 6, lane = tid & 63;
    const int wr = wave >> 1, wc = wave & 1;
    const int l15 = lane & 15, lh = lane >> 4;
    const int row0 = bx * 64;
    const int col0 = blockIdx.y * 128;

    const size_t aoff = (size_t)(row0 + (tid >> 2)) * j.Kp + (tid & 3) * 8;
    const size_t boff0 = (size_t)(col0 + (tid >> 2)) * j.Kp + (tid & 3) * 8;
    const size_t boff1 = boff0 + (size_t)64 * j.Kp;
    char* alds   = (char*)As + wave * 1024;
    char* blds0  = (char*)Bs + wave * 1024;
    char* blds1  = (char*)Bs + 4096 + wave * 1024;
    char* b2lds0 = (char*)B2s + wave * 1024;
    char* b2lds1 = (char*)B2s + 4096 + wave * 1024;

    f32x4 acc[2][4], acc2[2][4];
#pragma unroll
    for (int fm = 0; fm < 2; fm++)
#pragma unroll
        for (int fn = 0; fn < 4; fn++) {
            acc[fm][fn] = (f32x4)0.f;
            if (DUALW) acc2[fm][fn] = (f32x4)0.f;
        }

    for (int ks = 0; ks < j.ksteps; ks++) {
        const int k0 = ks * 32;
        __syncthreads();
        gl2lds16(j.A1 + aoff + k0, alds);
        gl2lds16(j.B1 + boff0 + k0, blds0);
        gl2lds16(j.B1 + boff1 + k0, blds1);
        if constexpr (DUALW) {
            gl2lds16(j.B2 + boff0 + k0, b2lds0);
            gl2lds16(j.B2 + boff1 + k0, b2lds1);
        }
        __syncthreads();

#pragma unroll
        for (int fm = 0; fm < 2; fm++) {
            bf16x8 a = *(const bf16x8*)&As[(wr * 32 + fm * 16 + l15) * 32 + lh * 8];
#pragma unroll
            for (int fn = 0; fn < 4; fn++) {
                bf16x8 b = *(const bf16x8*)&Bs[(wc * 64 + fn * 16 + l15) * 32 + lh * 8];
                acc[fm][fn] = __builtin_amdgcn_mfma_f32_16x16x32_bf16(a, b, acc[fm][fn], 0, 0, 0);
                if constexpr (DUALW) {
                    bf16x8 b2 = *(const bf16x8*)&B2s[(wc * 64 + fn * 16 + l15) * 32 + lh * 8];
                    acc2[fm][fn] = __builtin_amdgcn_mfma_f32_16x16x32_bf16(a, b2, acc2[fm][fn], 0, 0, 0);
                }
            }
        }
    }

    // ---- epilogue ----
    float bias[4], bias2[4];
#pragma unroll
    for (int fn = 0; fn < 4; fn++) {
        int col = col0 + wc * 64 + fn * 16 + l15;
        bias[fn] = 0.f; bias2[fn] = 0.f;
        if (col < j.N) {
            bias[fn] = j.b1[col];
            if (DUALW) bias2[fn] = j.b2[col];
        }
    }

    float vv[2][4][4];
#pragma unroll
    for (int fm = 0; fm < 2; fm++)
#pragma unroll
        for (int fn = 0; fn < 4; fn++)
#pragma unroll
            for (int r = 0; r < 4; r++) vv[fm][fn][r] = acc[fm][fn][r] + bias[fn];

    float scale[2][4];
#pragma unroll
    for (int fm = 0; fm < 2; fm++)
#pragma unroll
        for (int r = 0; r < 4; r++) scale[fm][r] = 1.f;

    if constexpr (ACT == 2) {
        float s[2][4];
#pragma unroll
        for (int fm = 0; fm < 2; fm++)
#pragma unroll
            for (int r = 0; r < 4; r++) {
                float v = 0.f;
#pragma unroll
                for (int fn = 0; fn < 4; fn++) v += vv[fm][fn][r] * vv[fm][fn][r];
                v += __shfl_xor(v, 1);
                v += __shfl_xor(v, 2);
                v += __shfl_xor(v, 4);
                v += __shfl_xor(v, 8);
                s[fm][r] = v;
            }
        __syncthreads();
        if (l15 == 0) {
#pragma unroll
            for (int fm = 0; fm < 2; fm++)
#pragma unroll
                for (int r = 0; r < 4; r++)
                    part[wc][wr * 32 + fm * 16 + lh * 4 + r] = s[fm][r];
        }
        __syncthreads();
#pragma unroll
        for (int fm = 0; fm < 2; fm++)
#pragma unroll
            for (int r = 0; r < 4; r++) {
                int rl = wr * 32 + fm * 16 + lh * 4 + r;
                float ss = part[0][rl] + part[1][rl];
                scale[fm][r] = 1.f / fmaxf(sqrtf(ss), 1e-12f);
            }
    }

#pragma unroll
    for (int fm = 0; fm < 2; fm++)
#pragma unroll
        for (int fn = 0; fn < 4; fn++)
#pragma unroll
            for (int r = 0; r < 4; r++) {
                int row = row0 + wr * 32 + fm * 16 + lh * 4 + r;
                int col = col0 + wc * 64 + fn * 16 + l15;
                if (row < j.M && col < j.N) {
                    float v = vv[fm][fn][r] * scale[fm][r];
                    if constexpr (EMIT == 0) j.O1[(size_t)row * j.N + col] = v;
                    if constexpr (EMIT == 2) j.Ob[(size_t)row * j.N + col] = (__bf16)v;
                    if constexpr (DUALW)
                        j.O2[(size_t)row * j.N + col] = (__bf16)(acc2[fm][fn][r] + bias2[fn]);
                }
            }
}

// =====================================================================
// Fused ea+wa: accL=x@Wl (shared), accP=rpp@Wrp, accG=rgp@Wrg;
// epilogue: app=elu(accL+accP+blp+brp), agp=elu(accL+accG+blp+brg),
// then per-(node,ch) type-softmax weights -> wpp/wgp fp32.
// =====================================================================
__global__ __launch_bounds__(256) void ea_wa_kernel(
    const __bf16* __restrict__ xb, const __bf16* __restrict__ rppb, const __bf16* __restrict__ rgpb,
    const __bf16* __restrict__ wl, const __bf16* __restrict__ wrp, const __bf16* __restrict__ wrg,
    const float* __restrict__ blp, const float* __restrict__ brp, const float* __restrict__ brg,
    const int* __restrict__ indeg_pp, const int* __restrict__ indeg_gp,
    float* __restrict__ wpp, float* __restrict__ wgp)
{
    __shared__ __align__(16) __bf16 A1s[64 * 32], A2s[64 * 32], A3s[64 * 32];
    __shared__ __align__(16) __bf16 B1s[128 * 32], B2s[128 * 32], B3s[128 * 32];

    const int tid = threadIdx.x;
    const int wave = tid >> 6, lane = tid & 63;
    const int wr = wave >> 1, wc = wave & 1;
    const int l15 = lane & 15, lh = lane >> 4;
    const int row0 = blockIdx.x * 64;

    const size_t aoff = (size_t)(row0 + (tid >> 2)) * 128 + (tid & 3) * 8;
    const size_t boff0 = (size_t)(tid >> 2) * 128 + (tid & 3) * 8;
    const size_t boff1 = boff0 + (size_t)64 * 128;
    char* a1 = (char*)A1s + wave * 1024;
    char* a2 = (char*)A2s + wave * 1024;
    char* a3 = (char*)A3s + wave * 1024;
    char* b1l0 = (char*)B1s + wave * 1024, *b1l1 = (char*)B1s + 4096 + wave * 1024;
    char* b2l0 = (char*)B2s + wave * 1024, *b2l1 = (char*)B2s + 4096 + wave * 1024;
    char* b3l0 = (char*)B3s + wave * 1024, *b3l1 = (char*)B3s + 4096 + wave * 1024;

    f32x4 accL[2][4], accP[2][4], accG[2][4];
#pragma unroll
    for (int fm = 0; fm < 2; fm++)
#pragma unroll
        for (int fn = 0; fn < 4; fn++) {
            accL[fm][fn] = (f32x4)0.f; accP[fm][fn] = (f32x4)0.f; accG[fm][fn] = (f32x4)0.f;
        }

    for (int ks = 0; ks < 4; ks++) {
        const int k0 = ks * 32;
        __syncthreads();
        gl2lds16(xb + aoff + k0, a1);
        gl2lds16(rppb + aoff + k0, a2);
        gl2lds16(rgpb + aoff + k0, a3);
        gl2lds16(wl + boff0 + k0, b1l0);  gl2lds16(wl + boff1 + k0, b1l1);
        gl2lds16(wrp + boff0 + k0, b2l0); gl2lds16(wrp + boff1 + k0, b2l1);
        gl2lds16(wrg + boff0 + k0, b3l0); gl2lds16(wrg + boff1 + k0, b3l1);
        __syncthreads();

#pragma unroll
        for (int fm = 0; fm < 2; fm++) {
            const int arow = (wr * 32 + fm * 16 + l15) * 32 + lh * 8;
            bf16x8 aL = *(const bf16x8*)&A1s[arow];
            bf16x8 aP = *(const bf16x8*)&A2s[arow];
            bf16x8 aG = *(const bf16x8*)&A3s[arow];
#pragma unroll
            for (int fn = 0; fn < 4; fn++) {
                const int brow = (wc * 64 + fn * 16 + l15) * 32 + lh * 8;
                bf16x8 bL = *(const bf16x8*)&B1s[brow];
                bf16x8 bP = *(const bf16x8*)&B2s[brow];
                bf16x8 bG = *(const bf16x8*)&B3s[brow];
                accL[fm][fn] = __builtin_amdgcn_mfma_f32_16x16x32_bf16(aL, bL, accL[fm][fn], 0, 0, 0);
                accP[fm][fn] = __builtin_amdgcn_mfma_f32_16x16x32_bf16(aP, bP, accP[fm][fn], 0, 0, 0);
                accG[fm][fn] = __builtin_amdgcn_mfma_f32_16x16x32_bf16(aG, bG, accG[fm][fn], 0, 0, 0);
            }
        }
    }

    float bp[4], bg[4];
#pragma unroll
    for (int fn = 0; fn < 4; fn++) {
        int col = wc * 64 + fn * 16 + l15;
        bp[fn] = blp[col] + brp[col];
        bg[fn] = blp[col] + brg[col];
    }

#pragma unroll
    for (int fm = 0; fm < 2; fm++)
#pragma unroll
        for (int r = 0; r < 4; r++) {
            int row = row0 + wr * 32 + fm * 16 + lh * 4 + r;
            int rr = min(row, NP - 1);
            int npp = indeg_pp[rr], ngp = indeg_gp[rr];
#pragma unroll
            for (int fn = 0; fn < 4; fn++) {
                int col = wc * 64 + fn * 16 + l15;
                float app = accL[fm][fn][r] + accP[fm][fn][r] + bp[fn];
                app = app > 0.f ? app : (__expf(app) - 1.f);
                float agp = accL[fm][fn][r] + accG[fm][fn][r] + bg[fn];
                agp = agp > 0.f ? agp : (__expf(agp) - 1.f);
                float wppv = 0.f, wgpv = 0.f;
                if (npp > 0 && ngp > 0) {
                    float mx = fmaxf(app, agp);
                    float ep = __expf(app - mx), eg = __expf(agp - mx);
                    float den = (float)npp * ep + (float)ngp * eg;
                    wppv = ep / den; wgpv = eg / den;
                } else if (npp > 0) wppv = 1.f / (float)npp;
                else if (ngp > 0) wgpv = 1.f / (float)ngp;
                if (row < NP) {
                    wpp[(size_t)row * DH + col] = wppv;
                    wgp[(size_t)row * DH + col] = wgpv;
                }
            }
        }
}

// ---------------- GCN aggregation: barrier-free, broadcast edge records, unroll-4 ----------------
__global__ __launch_bounds__(128) void rst_agg_kernel(const __bf16* __restrict__ x,
                                                      const int* __restrict__ row_ptr,
                                                      const int2* __restrict__ edata,
                                                      const int* __restrict__ indeg_pp,
                                                      const int* __restrict__ indeg_gp,
                                                      __bf16* __restrict__ rppb, __bf16* __restrict__ rgpb)
{
    const int d = blockIdx.x;  // < NP
    const int c = threadIdx.x;
    const int beg = row_ptr[d], end = row_ptr[d + 1];
    float spp = 0.f, sgp = 0.f;
    const unsigned short* xu = (const unsigned short*)x;
    int i = beg;
    for (; i + 3 < end; i += 4) {
        int2 e0 = edata[i], e1 = edata[i + 1], e2 = edata[i + 2], e3 = edata[i + 3];
        float v0 = b2f(xu[(size_t)(e0.x & 0xFFFF) * DH + c]) * __int_as_float(e0.y);
        float v1 = b2f(xu[(size_t)(e1.x & 0xFFFF) * DH + c]) * __int_as_float(e1.y);
        float v2 = b2f(xu[(size_t)(e2.x & 0xFFFF) * DH + c]) * __int_as_float(e2.y);
        float v3 = b2f(xu[(size_t)(e3.x & 0xFFFF) * DH + c]) * __int_as_float(e3.y);
        if ((e0.x >> 16) == 0) spp += v0; else sgp += v0;
        if ((e1.x >> 16) == 0) spp += v1; else sgp += v1;
        if ((e2.x >> 16) == 0) spp += v2; else sgp += v2;
        if ((e3.x >> 16) == 0) spp += v3; else sgp += v3;
    }
    for (; i < end; i++) {
        int2 e0 = edata[i];
        float v0 = b2f(xu[(size_t)(e0.x & 0xFFFF) * DH + c]) * __int_as_float(e0.y);
        if ((e0.x >> 16) == 0) spp += v0; else sgp += v0;
    }
    float ipp = rsqrtf((float)max(indeg_pp[d], 1));
    float igp = rsqrtf((float)max(indeg_gp[d], 1));
    rppb[(size_t)d * DH + c] = (__bf16)(spp * ipp);
    rgpb[(size_t)d * DH + c] = (__bf16)(sgp * igp);
}

// ---------------- pack xb + hlb -> interleaved dwords {x(lo), hl(hi)} ----------------
__global__ __launch_bounds__(256) void pack_xhl_kernel(const unsigned int* __restrict__ xb2,
                                                       const unsigned int* __restrict__ hl2,
                                                       uint4* __restrict__ xhl4)
{
    int i = blockIdx.x * 256 + threadIdx.x;   // one uint4 out = 4 channels
    if (i >= 25024 * 128 / 4) return;
    unsigned int xa = xb2[i * 2], xbv = xb2[i * 2 + 1];
    unsigned int ha = hl2[i * 2], hbv = hl2[i * 2 + 1];
    uint4 o;
    o.x = (xa & 0xFFFFu) | (ha << 16);
    o.y = (xa >> 16) | (ha & 0xFFFF0000u);
    o.z = (xbv & 0xFFFFu) | (hbv << 16);
    o.w = (xbv >> 16) | (hbv & 0xFFFF0000u);
    xhl4[i] = o;
}

// ---------------- node attention: barrier-free, packed dword gather, unroll-4 ----------------
__global__ __launch_bounds__(128) void node_attn_kernel(const unsigned int* __restrict__ xhl,
                                                        const __bf16* __restrict__ hrb,
                                                        const float* __restrict__ wpp_arr,
                                                        const float* __restrict__ wgp_arr,
                                                        const int* __restrict__ indeg_pg,
                                                        const int* __restrict__ row_ptr,
                                                        const int2* __restrict__ edata,
                                                        __bf16* __restrict__ hb)
{
    const int d = blockIdx.x;
    const int c = threadIdx.x;
    const int beg = row_ptr[d], end = row_ptr[d + 1];
    const float hrd = b2f(((const unsigned short*)hrb)[(size_t)d * DH + c]);
    float wppv, wgpv;
    if (d < NP) {
        wppv = wpp_arr[(size_t)d * DH + c];
        wgpv = wgp_arr[(size_t)d * DH + c];
    } else {
        float w = 1.f / (float)max(indeg_pg[d - NP], 1);
        wppv = w; wgpv = w;
    }
    float ssum = 0.f, acc = 0.f;

    auto body = [&](int p) {
        unsigned int u = xhl[(size_t)(p & 0xFFFF) * 128 + c];
        float xv  = b2f((unsigned short)(u & 0xFFFFu));
        float hlv = b2f((unsigned short)(u >> 16));
        float al = ((p >> 16) == 0) ? wppv : wgpv;
        float e = (hlv + hrd) * al;
        e = fmaxf(e, -0.2f * e);          // LeakyReLU slope -0.2
        float pw = __expf(e);
        ssum += pw;
        acc += pw * xv;
    };

    int i = beg;
    for (; i + 3 < end; i += 4) {
        int p0 = edata[i].x, p1 = edata[i + 1].x, p2 = edata[i + 2].x, p3 = edata[i + 3].x;
        unsigned int u0 = xhl[(size_t)(p0 & 0xFFFF) * 128 + c];
        unsigned int u1 = xhl[(size_t)(p1 & 0xFFFF) * 128 + c];
        unsigned int u2 = xhl[(size_t)(p2 & 0xFFFF) * 128 + c];
        unsigned int u3 = xhl[(size_t)(p3 & 0xFFFF) * 128 + c];
#pragma unroll
        for (int k = 0; k < 4; k++) {
            unsigned int u = (k == 0) ? u0 : (k == 1) ? u1 : (k == 2) ? u2 : u3;
            int p = (k == 0) ? p0 : (k == 1) ? p1 : (k == 2) ? p2 : p3;
            float xv  = b2f((unsigned short)(u & 0xFFFFu));
            float hlv = b2f((unsigned short)(u >> 16));
            float al = ((p >> 16) == 0) ? wppv : wgpv;
            float e = (hlv + hrd) * al;
            e = fmaxf(e, -0.2f * e);
            float pw = __expf(e);
            ssum += pw;
            acc += pw * xv;
        }
    }
    for (; i < end; i++) body(edata[i].x);

    hb[(size_t)d * DH + c] = (__bf16)((end > beg) ? acc / ssum : 0.f);
}

extern "C" void kernel_launch(void* const* d_in, const int* in_sizes, int n_in,
                              void* d_out, int out_size, void* d_ws, size_t ws_size,
                              hipStream_t stream)
{
    const float* x_protein = (const float*)d_in[0];
    const float* x_go      = (const float*)d_in[1];
    const int* src_pp = (const int*)d_in[2];
    const int* dst_pp = (const int*)d_in[3];
    const int* src_pg = (const int*)d_in[4];
    const int* dst_pg = (const int*)d_in[5];
    const int* src_gp = (const int*)d_in[6];
    const int* dst_gp = (const int*)d_in[7];
    const float* W1p = (const float*)d_in[8];
    const float* b1p = (const float*)d_in[9];
    const float* W1g = (const float*)d_in[10];
    const float* b1g = (const float*)d_in[11];
    const float* Wl_p = (const float*)d_in[12];
    const float* bl_p = (const float*)d_in[13];
    // Wl_g (14), bl_g (15) dead: go-dst type-alpha is uniform 1/n
    const float* Wr_p = (const float*)d_in[16];
    const float* br_p = (const float*)d_in[17];
    const float* Wr_g = (const float*)d_in[18];
    const float* br_g = (const float*)d_in[19];
    const float* Wnl = (const float*)d_in[20];
    const float* bnl = (const float*)d_in[21];
    const float* Wnr = (const float*)d_in[22];
    const float* bnr = (const float*)d_in[23];
    const float* Wfc = (const float*)d_in[24];
    const float* bfc = (const float*)d_in[25];
    float* out = (float*)d_out;

    // ---- workspace layout (4B words); total ~69 MB ----
    size_t off = 0;
    char* base = (char*)d_ws;
    auto alloc = [&](size_t words) { void* p = base + off * 4; off += (words + 7) & ~(size_t)7; return p; };

    __bf16* xb  = (__bf16*)alloc((size_t)25024 * 128 / 2);   // x bf16 dense
    __bf16* hlb = (__bf16*)alloc((size_t)25024 * 128 / 2);   // hl bf16 dense
    __bf16* hrb = (__bf16*)alloc((size_t)25024 * 128 / 2);   // hr bf16 dense
    // U region: rppb+rgpb (10.25MB) until ea_wa; xhl (12.8MB) after hlr
    char* U = (char*)alloc((size_t)25024 * 128);             // 3,203,072 words
    __bf16* rppb = (__bf16*)U;                               // 20032*128
    __bf16* rgpb = (__bf16*)(U + (size_t)20032 * 128 * 2);
    unsigned int* xhl = (unsigned int*)U;                    // 25024*128 dwords
    // R1: hist partials -> (xpb, xgb) -> (wpp, wgp, haggb)
    char* R1 = (char*)alloc((size_t)5128192 + 2588672);
    int*    partial = (int*)R1;                              // 16*90000 ints
    __bf16* xpb = (__bf16*)R1;                               // 20032*512
    __bf16* xgb = (__bf16*)(R1 + (size_t)20032 * 512 * 2);   // 5056*1024
    float*  wpp = (float*)R1;                                // 20000*128 f32
    float*  wgp = wpp + (size_t)20000 * 128;
    __bf16* haggb = (__bf16*)(wgp + (size_t)20000 * 128);    // 25024*128
    __bf16* w1pt = (__bf16*)alloc(128 * 512 / 2);
    __bf16* w1gt = (__bf16*)alloc(128 * 1024 / 2);
    __bf16* wlpt = (__bf16*)alloc(128 * 128 / 2);
    __bf16* wrpt = (__bf16*)alloc(128 * 128 / 2);
    __bf16* wrgt = (__bf16*)alloc(128 * 128 / 2);
    __bf16* wnlt = (__bf16*)alloc(128 * 128 / 2);
    __bf16* wnrt = (__bf16*)alloc(128 * 128 / 2);
    __bf16* wfct = (__bf16*)alloc(1024 * 128 / 2);
    int* outdeg_pp = (int*)alloc(NP);
    int* outdeg_pg = (int*)alloc(NP);
    int* outdeg_gp = (int*)alloc(NG);
    int* indeg_pp  = (int*)alloc(NP);
    int* indeg_gp  = (int*)alloc(NP);
    int* indeg_pg  = (int*)alloc(NG);
    int* fill      = (int*)alloc((size_t)NTOT * FS);
    int* row_ptr   = (int*)alloc(NTOT + 1);
    int2* edata    = (int2*)alloc((size_t)ETOT * 2);

    hipMemsetAsync(fill, 0, (size_t)NTOT * FS * sizeof(int), stream);

    hist_part_kernel<<<dim3(HB, 6), 1024, 0, stream>>>(
        src_pp, dst_pp, src_pg, dst_pg, src_gp, dst_gp, partial);
    hist_merge_kernel<<<dim3((20000 + 255) / 256, 6), 256, 0, stream>>>(
        partial, outdeg_pp, indeg_pp, outdeg_pg, indeg_pg, outdeg_gp, indeg_gp);
    scan_kernel<<<1, 1024, 0, stream>>>(indeg_pp, indeg_gp, indeg_pg, row_ptr);
    scatter_kernel<<<(ETOT + 255) / 256, 256, 0, stream>>>(
        src_pp, dst_pp, src_pg, dst_pg, src_gp, dst_gp,
        outdeg_pp, outdeg_pg, outdeg_gp, row_ptr, fill, edata);

    conv_x_kernel<<<dim3(5008, 2), 256, 0, stream>>>(x_protein, x_go, xpb, xgb);
    conv_w_kernel<<<dim3(512, 8), 256, 0, stream>>>(W1p, W1g, Wl_p, Wr_p, Wr_g, Wnl, Wnr, Wfc,
                                                    w1pt, w1gt, wlpt, wrpt, wrgt, wnlt, wnrt, wfct);

    // fused projections + l2norm -> xb (bf16)
    {
        GJob p0 = { xpb, w1pt, nullptr, b1p, nullptr, nullptr, nullptr, xb, NP, 128, 512, 16 };
        GJob p1 = { xgb, w1gt, nullptr, b1g, nullptr, nullptr, nullptr,
                    xb + (size_t)NP * 128, NG, 128, 1024, 32 };
        gemm_bt<2, 0, 2><<<392, 256, 0, stream>>>(p0, p1, 313);
    }

    // GCN aggregation for type attention (protein dst only)
    rst_agg_kernel<<<NP, 128, 0, stream>>>(xb, row_ptr, edata, indeg_pp, indeg_gp, rppb, rgpb);

    // fused ea + type-softmax weights -> wpp/wgp (fp32)
    ea_wa_kernel<<<313, 256, 0, stream>>>(xb, rppb, rgpb, wlpt, wrpt, wrgt,
                                          bl_p, br_p, br_g, indeg_pp, indeg_gp, wpp, wgp);

    // node attention projections: hl (bf16 dense) + hr (bf16 dense)
    {
        GJob h0 = { xb, wnlt, wnrt, bnl, bnr, nullptr, hrb, hlb, NTOT, 128, 128, 4 };
        gemm_bt<0, 1, 2><<<391, 256, 0, stream>>>(h0, h0, 1 << 30);
    }

    // pack {x, hl} -> xhl dwords (rppb/rgpb dead after ea_wa)
    pack_xhl_kernel<<<3128, 256, 0, stream>>>((const unsigned int*)xb, (const unsigned int*)hlb, (uint4*)xhl);

    // node attention + aggregation -> haggb
    node_attn_kernel<<<NTOT, 128, 0, stream>>>(xhl, hrb, wpp, wgp, indeg_pg, row_ptr, edata, haggb);

    // final classifier: out = hagg@Wfc + bfc
    {
        GJob o0 = { haggb, wfct, nullptr, bfc, nullptr, out, nullptr, nullptr, NTOT, NCLS, 128, 4 };
        gemm_bt<0, 0, 0><<<dim3(391, 8), 256, 0, stream>>>(o0, o0, 1 << 30);
    }

    (void)in_sizes; (void)n_in; (void)out_size; (void)ws_size;
}